// Round 1
// baseline (1044.145 us; speedup 1.0000x reference)
//
#include <hip/hip_runtime.h>
#include <math.h>

#define HID    64
#define MSTEPS 60
#define NPTS   32
#define RPTSC  128
#define BTOT   (RPTSC*NPTS)    // 4096 paths
#define NSIM   (2*BTOT)        // 8192 path-branches (antithetic)

// hard-coded model constants (match reference, fp32 semantics)
#define C_DT     0.025f
#define C_SQDT   0.15811388300841897f   // sqrt(0.025)
#define C_ALPHA  0.8f
#define C_RHO    0.3f
#define C_SQ1MR2 0.9539392014169456f    // sqrt(1-0.09)
#define C_KAPPA  1.2f
#define C_R      0.02f
#define C_SIGMA  0.2f
#define C_SIGY   0.3f
#define C_LBW    1e-3f

__device__ __forceinline__ float rlane(float v, int l) {
    return __int_as_float(__builtin_amdgcn_readlane(__float_as_int(v), l));
}

__global__ void zero_ws(float* ws) {
    ws[threadIdx.x] = 0.0f;   // 96 floats: S1[32], S2[32], S3[32]
}

__global__ __launch_bounds__(256) void sim_kernel(
    const float* __restrict__ noise,
    const float* __restrict__ w1, const float* __restrict__ b1,
    const float* __restrict__ w2, const float* __restrict__ b2,
    const float* __restrict__ w3, const float* __restrict__ b3,
    const float* __restrict__ Wp, const float* __restrict__ Yp,
    float* __restrict__ ws)
{
    const int lane = threadIdx.x & 63;
    const int wid  = (blockIdx.x * blockDim.x + threadIdx.x) >> 6;  // 0..8191
    if (wid >= NSIM) return;
    const int simb = wid >> 12;          // 0: anti=+1 branch, 1: anti=-1 branch
    const int b    = wid & (BTOT - 1);   // path index 0..4095
    const int i    = b & (NPTS - 1);     // eval-point index (b = r*32 + i)
    const float anti = simb ? -1.0f : 1.0f;

    // per-lane (= per hidden unit) weights
    const float cW  = w1[lane];          // w1[0][k] : d a1/dW (constant)
    const float cT  = w1[HID + lane];    // w1[1][k]
    const float cYw = w1[2*HID + lane];  // w1[2][k] : d a1/dY (constant)
    const float b1k = b1[lane];
    const float b2k = b2[lane];
    const float w3k = w3[lane];
    const float b3v = b3[0];
    const float cW2 = cW * cW;
    const float cWYc = cW * cYw;

    float w2c[HID];
    #pragma unroll
    for (int j = 0; j < HID; ++j) w2c[j] = w2[j*HID + lane];  // w2[j][k]

    // noise base offsets: noise[sim][draw][m][b]
    const long zb1 = (long)(simb*2 + 0) * MSTEPS * BTOT + b;
    const long zb2 = (long)(simb*2 + 1) * MSTEPS * BTOT + b;

    // state + jets of L = logW: gW=dL/dW0, gY=dL/dY0, hWW=d2L/dW0^2, hWY=d2L/dW0dY0
    const float W0 = Wp[i];
    float L   = logf(fmaxf(W0, C_LBW));
    float Yv  = Yp[i];
    float tmt = 1.5f;
    float gW  = 1.0f / W0;
    float hWW = -gW * gW;
    float gY  = 0.0f, hWY = 0.0f;
    float cYt = 1.0f;                       // dY_t/dY0 = (1-kappa*dt)^t
    const float cYfac = 1.0f - C_KAPPA * C_DT;

    #pragma unroll 1
    for (int m = 0; m < MSTEPS; ++m) {
        const float z1 = noise[zb1 + (long)m * BTOT];
        const float z2 = noise[zb2 + (long)m * BTOT];

        const float W = expf(L);
        // ---- layer 1 + tanh, build 5 channel inputs (value, dW, dY, dWW, dWY)
        const float a1 = fmaf(W, cW, fmaf(tmt, cT, fmaf(Yv, cYw, b1k)));
        const float t  = tanhf(a1);
        const float dp = 1.0f - t * t;         // tanh'
        const float ddp = -2.0f * t * dp;      // tanh''
        const float s0 = t;
        const float s1 = dp * cW;
        const float s2 = dp * cYw;
        const float s3 = ddp * cW2;
        const float s4 = ddp * cWYc;

        // ---- layer 2: a2_c[k] = sum_j s_c[j] * w2[j][k]
        float a0 = b2k, aW = 0.0f, aY = 0.0f, aWW = 0.0f, aWY = 0.0f;
        #pragma unroll
        for (int j = 0; j < HID; ++j) {
            const float w = w2c[j];
            a0  = fmaf(rlane(s0, j), w, a0);
            aW  = fmaf(rlane(s1, j), w, aW);
            aY  = fmaf(rlane(s2, j), w, aY);
            aWW = fmaf(rlane(s3, j), w, aWW);
            aWY = fmaf(rlane(s4, j), w, aWY);
        }

        // ---- tanh with full second-order jets
        const float t2  = tanhf(a0);
        const float d2  = 1.0f - t2 * t2;
        const float dd2 = -2.0f * t2 * d2;
        const float h0 = t2;
        const float h1 = d2 * aW;
        const float h2 = d2 * aY;
        const float h3 = fmaf(dd2 * aW, aW, d2 * aWW);
        const float h4 = fmaf(dd2 * aW, aY, d2 * aWY);

        // ---- layer 3: 5 dot products over lanes
        float p0 = h0 * w3k, p1 = h1 * w3k, p2 = h2 * w3k, p3 = h3 * w3k, p4 = h4 * w3k;
        #pragma unroll
        for (int off = 32; off >= 1; off >>= 1) {
            p0 += __shfl_xor(p0, off, 64);
            p1 += __shfl_xor(p1, off, 64);
            p2 += __shfl_xor(p2, off, 64);
            p3 += __shfl_xor(p3, off, 64);
            p4 += __shfl_xor(p4, off, 64);
        }
        const float pi  = p0 + b3v;            // policy value
        const float pW  = p1, pY = p2, pWW = p3, pWY = p4;  // derivs wrt (W,Y)
        // convert W-derivs to L-derivs (W = e^L)
        const float piL  = pW * W;
        const float piLL = fmaf(pWW, W * W, pW * W);
        const float piY  = pY;
        const float piLY = pWY * W;

        const float zW = anti * z1;
        const float zY = anti * (C_RHO * z1 + C_SQ1MR2 * z2);
        const float Sn = C_SIGMA * C_SQDT * zW;               // sigma*sqrt(dt)*zW
        const float G  = C_SIGMA * C_ALPHA * Yv - pi * (C_SIGMA * C_SIGMA);  // dDrift/dpi

        const float drift = C_R + pi * (C_SIGMA * C_ALPHA * Yv);
        const float var   = (pi * C_SIGMA) * (pi * C_SIGMA);
        const float Lnew  = L + (drift - 0.5f * var) * C_DT + pi * Sn;

        // step-map partials F(L,Y)
        const float F_L  = 1.0f + (G * piL) * C_DT + piL * Sn;
        const float F_Y  = (G * piY + pi * C_SIGMA * C_ALPHA) * C_DT + piY * Sn;
        const float F_LL = (G * piLL - C_SIGMA * C_SIGMA * piL * piL) * C_DT + piLL * Sn;
        const float F_LY = (G * piLY - C_SIGMA * C_SIGMA * piL * piY + C_SIGMA * C_ALPHA * piL) * C_DT
                           + piLY * Sn;

        // jet updates (use old values on RHS)
        const float hWWn = F_LL * gW * gW + F_L * hWW;
        const float hWYn = F_LL * gW * gY + F_LY * gW * cYt + F_L * hWY;
        const float gWn  = F_L * gW;
        const float gYn  = F_L * gY + F_Y * cYt;

        // Y update (linear, independent of W)
        Yv  = Yv + C_KAPPA * (0.0f - Yv) * C_DT + C_SIGY * C_SQDT * zY;
        cYt *= cYfac;

        // clip W at LB_W (replicate ref's exp/log round-trip)
        const float We = expf(Lnew);
        if (We < C_LBW) {
            L = logf(C_LBW);
            gW = 0.0f; gY = 0.0f; hWW = 0.0f; hWY = 0.0f;
        } else {
            L = logf(We);
            gW = gWn; gY = gYn; hWW = hWWn; hWY = hWYn;
        }
        tmt -= C_DT;
    }

    // terminal utility U = W_T^(1-5)/(1-5) = -0.25*exp(-4L); dU/dL = E, d2U/dL2 = -4E
    const float E  = expf(-4.0f * L);
    const float d1 = E * gW;                                  // dU/dW0
    const float d2v = fmaf(-4.0f * E, gW * gW, E * hWW);      // d2U/dW0^2
    const float d3v = fmaf(-4.0f * E, gW * gY, E * hWY);      // d2U/dW0dY0

    if (lane == 0) {
        atomicAdd(&ws[i],          0.5f * d1);
        atomicAdd(&ws[NPTS + i],   0.5f * d2v);
        atomicAdd(&ws[2*NPTS + i], 0.5f * d3v);
    }
}

__global__ void proj_kernel(const float* __restrict__ ws,
                            const float* __restrict__ Wp,
                            const float* __restrict__ Yp,
                            float* __restrict__ out)
{
    const int i = threadIdx.x;
    if (i >= NPTS) return;
    // lam = S1/128^3 ; dlamW,dlamY = S2,S3/128^4  (exact powers of two)
    const float lam   = ws[i]          * (1.0f / 2097152.0f);
    const float dlamW = ws[NPTS + i]   * (1.0f / 268435456.0f);
    const float dlamY = ws[2*NPTS + i] * (1.0f / 268435456.0f);
    const float Wv = Wp[i], Yv = Yp[i];
    const float mmr   = C_SIGMA * (C_ALPHA * Yv);
    const float sig2  = C_SIGMA * C_SIGMA;
    const float coeff = -1.0f / (Wv * dlamW + 1e-8f);
    const float myo   = coeff * (lam * (mmr / sig2));
    const float hedge = coeff * (C_SIGMA * C_RHO * C_SIGY * dlamY / sig2);
    float v = myo + hedge;
    v = fminf(fmaxf(v, -2.0f), 2.0f);
    out[i] = v;
}

extern "C" void kernel_launch(void* const* d_in, const int* in_sizes, int n_in,
                              void* d_out, int out_size, void* d_ws, size_t ws_size,
                              hipStream_t stream) {
    const float* Wp    = (const float*)d_in[0];
    // d_in[1] = TmT (unused: reference simulates from T_H constant)
    const float* Yp    = (const float*)d_in[2];
    const float* noise = (const float*)d_in[3];
    const float* w1    = (const float*)d_in[4];
    const float* b1    = (const float*)d_in[5];
    const float* w2    = (const float*)d_in[6];
    const float* b2    = (const float*)d_in[7];
    const float* w3    = (const float*)d_in[8];
    const float* b3    = (const float*)d_in[9];
    float* out = (float*)d_out;
    float* ws  = (float*)d_ws;

    hipLaunchKernelGGL(zero_ws, dim3(1), dim3(96), 0, stream, ws);
    hipLaunchKernelGGL(sim_kernel, dim3(NSIM/4), dim3(256), 0, stream,
                       noise, w1, b1, w2, b2, w3, b3, Wp, Yp, ws);
    hipLaunchKernelGGL(proj_kernel, dim3(1), dim3(64), 0, stream, ws, Wp, Yp, out);
}

// Round 2
// 642.602 us; speedup vs baseline: 1.6249x; 1.6249x over previous
//
#include <hip/hip_runtime.h>
#include <math.h>

#define HID    64
#define MSTEPS 60
#define NPTS   32
#define RPTSC  128
#define BTOT   (RPTSC*NPTS)    // 4096 paths
#define NSIM   (2*BTOT)        // 8192 path-branches (antithetic)

// hard-coded model constants (match reference, fp32 semantics)
#define C_DT     0.025f
#define C_SQDT   0.15811388300841897f   // sqrt(0.025)
#define C_ALPHA  0.8f
#define C_RHO    0.3f
#define C_SQ1MR2 0.9539392014169456f    // sqrt(1-0.09)
#define C_KAPPA  1.2f
#define C_R      0.02f
#define C_SIGMA  0.2f
#define C_SIGY   0.3f
#define C_LBW    1e-3f
#define C_LOGLBW -6.907755279f          // log(1e-3)

typedef float v2f __attribute__((ext_vector_type(2)));

__device__ __forceinline__ float rlane(float v, int l) {
    return __int_as_float(__builtin_amdgcn_readlane(__float_as_int(v), l));
}

// tanh(x) = 1 - 2/(e^{2x}+1); v_exp + v_rcp, ~1e-6 rel err, saturates correctly
__device__ __forceinline__ float ftanh(float x) {
    float e = __expf(2.0f * x);
    return 1.0f - 2.0f * __builtin_amdgcn_rcpf(e + 1.0f);
}

__global__ void zero_ws(float* ws) {
    ws[threadIdx.x] = 0.0f;   // 96 floats: S1[32], S2[32], S3[32]
}

__global__ __launch_bounds__(256, 2) void sim_kernel(
    const float* __restrict__ noise,
    const float* __restrict__ w1, const float* __restrict__ b1,
    const float* __restrict__ w2, const float* __restrict__ b2,
    const float* __restrict__ w3, const float* __restrict__ b3,
    const float* __restrict__ Wp, const float* __restrict__ Yp,
    float* __restrict__ ws)
{
    const int lane = threadIdx.x & 63;
    // wave id; readfirstlane -> provably wave-uniform so noise loads scalarize
    const int wid = __builtin_amdgcn_readfirstlane(
        (int)((blockIdx.x * blockDim.x + threadIdx.x) >> 6));   // 0..8191
    const int simb = wid >> 12;          // 0: anti=+1 branch, 1: anti=-1 branch
    const int b    = wid & (BTOT - 1);   // path index 0..4095
    const int i    = b & (NPTS - 1);     // eval-point index (b = r*32 + i)
    const float anti = simb ? -1.0f : 1.0f;

    // per-lane (= per hidden unit) weights
    const float cW  = w1[lane];          // w1[0][k] : d a1/dW (constant)
    const float cT  = w1[HID + lane];    // w1[1][k]
    const float cYw = w1[2*HID + lane];  // w1[2][k] : d a1/dY (constant)
    const float b1k = b1[lane];
    const float b2k = b2[lane];
    const float w3k = w3[lane];
    const float b3v = b3[0];
    const float cW2  = cW * cW;
    const float cWYc = cW * cYw;

    // pin w2 columns in VGPRs as 32 float2 pairs (paired along j)
    v2f w2p[32];
    #pragma unroll
    for (int jj = 0; jj < 32; ++jj) {
        w2p[jj] = v2f{ w2[(2*jj)*HID + lane], w2[(2*jj+1)*HID + lane] };
    }

    // uniform noise base pointers: noise[sim][draw][m][b]
    const float* zp1 = noise + (size_t)(simb*2 + 0) * MSTEPS * BTOT + b;
    const float* zp2 = noise + (size_t)(simb*2 + 1) * MSTEPS * BTOT + b;

    // state + jets of L = logW: gW=dL/dW0, gY=dL/dY0, hWW=d2L/dW0^2, hWY=d2L/dW0dY0
    const float W0 = Wp[i];
    float L   = __logf(fmaxf(W0, C_LBW));
    float W   = __expf(L);
    float Yv  = Yp[i];
    float tmt = 1.5f;
    float gW  = 1.0f / W0;
    float hWW = -gW * gW;
    float gY  = 0.0f, hWY = 0.0f;
    float cYt = 1.0f;                       // dY_t/dY0 = (1-kappa*dt)^t
    const float cYfac = 1.0f - C_KAPPA * C_DT;

    #pragma unroll 1
    for (int m = 0; m < MSTEPS; ++m) {
        const float z1 = zp1[m * BTOT];     // uniform -> s_load
        const float z2 = zp2[m * BTOT];

        // ---- layer 1 + tanh, build 5 channel inputs (value, dW, dY, dWW, dWY)
        const float a1 = fmaf(W, cW, fmaf(tmt, cT, fmaf(Yv, cYw, b1k)));
        const float t  = ftanh(a1);
        const float dp = 1.0f - t * t;         // tanh'
        const float ddp = -2.0f * t * dp;      // tanh''
        const float s0 = t;
        const float s1 = dp * cW;
        const float s2 = dp * cYw;
        const float s3 = ddp * cW2;
        const float s4 = ddp * cWYc;

        // ---- layer 2: a2_c[k] = sum_j s_c[j] * w2[j][k], packed 2 j's per fma
        v2f A0 = {0.0f, 0.0f}, AW = {0.0f, 0.0f}, AY = {0.0f, 0.0f};
        v2f AWW = {0.0f, 0.0f}, AWY = {0.0f, 0.0f};
        #pragma unroll
        for (int jj = 0; jj < 32; ++jj) {
            const int j0 = 2*jj, j1 = 2*jj + 1;
            const v2f wv = w2p[jj];
            v2f S0 = { rlane(s0, j0), rlane(s0, j1) };
            v2f S1 = { rlane(s1, j0), rlane(s1, j1) };
            v2f S2 = { rlane(s2, j0), rlane(s2, j1) };
            v2f S3 = { rlane(s3, j0), rlane(s3, j1) };
            v2f S4 = { rlane(s4, j0), rlane(s4, j1) };
            A0  = __builtin_elementwise_fma(S0, wv, A0);
            AW  = __builtin_elementwise_fma(S1, wv, AW);
            AY  = __builtin_elementwise_fma(S2, wv, AY);
            AWW = __builtin_elementwise_fma(S3, wv, AWW);
            AWY = __builtin_elementwise_fma(S4, wv, AWY);
        }
        const float a0  = A0.x + A0.y + b2k;
        const float aW  = AW.x + AW.y;
        const float aY  = AY.x + AY.y;
        const float aWW = AWW.x + AWW.y;
        const float aWY = AWY.x + AWY.y;

        // ---- tanh with full second-order jets
        const float t2  = ftanh(a0);
        const float d2  = 1.0f - t2 * t2;
        const float dd2 = -2.0f * t2 * d2;
        const float h0 = t2;
        const float h1 = d2 * aW;
        const float h2 = d2 * aY;
        const float h3 = fmaf(dd2 * aW, aW, d2 * aWW);
        const float h4 = fmaf(dd2 * aW, aY, d2 * aWY);

        // ---- layer 3: 5 dot products over lanes
        float p0 = h0 * w3k, p1 = h1 * w3k, p2 = h2 * w3k, p3 = h3 * w3k, p4 = h4 * w3k;
        #pragma unroll
        for (int off = 32; off >= 1; off >>= 1) {
            p0 += __shfl_xor(p0, off, 64);
            p1 += __shfl_xor(p1, off, 64);
            p2 += __shfl_xor(p2, off, 64);
            p3 += __shfl_xor(p3, off, 64);
            p4 += __shfl_xor(p4, off, 64);
        }
        const float pi  = p0 + b3v;            // policy value
        const float pW  = p1, pY = p2, pWW = p3, pWY = p4;  // derivs wrt (W,Y)
        // convert W-derivs to L-derivs (W = e^L)
        const float piL  = pW * W;
        const float piLL = fmaf(pWW, W * W, pW * W);
        const float piY  = pY;
        const float piLY = pWY * W;

        const float zW = anti * z1;
        const float zY = anti * (C_RHO * z1 + C_SQ1MR2 * z2);
        const float Sn = C_SIGMA * C_SQDT * zW;               // sigma*sqrt(dt)*zW
        const float G  = C_SIGMA * C_ALPHA * Yv - pi * (C_SIGMA * C_SIGMA);  // dDrift/dpi

        const float drift = C_R + pi * (C_SIGMA * C_ALPHA * Yv);
        const float var   = (pi * C_SIGMA) * (pi * C_SIGMA);
        const float Lnew  = L + (drift - 0.5f * var) * C_DT + pi * Sn;

        // step-map partials F(L,Y)
        const float F_L  = 1.0f + (G * piL) * C_DT + piL * Sn;
        const float F_Y  = (G * piY + pi * C_SIGMA * C_ALPHA) * C_DT + piY * Sn;
        const float F_LL = (G * piLL - C_SIGMA * C_SIGMA * piL * piL) * C_DT + piLL * Sn;
        const float F_LY = (G * piLY - C_SIGMA * C_SIGMA * piL * piY + C_SIGMA * C_ALPHA * piL) * C_DT
                           + piLY * Sn;

        // jet updates (use old values on RHS)
        const float hWWn = F_LL * gW * gW + F_L * hWW;
        const float hWYn = F_LL * gW * gY + F_LY * gW * cYt + F_L * hWY;
        const float gWn  = F_L * gW;
        const float gYn  = F_L * gY + F_Y * cYt;

        // Y update (linear, independent of W)
        Yv  = Yv + C_KAPPA * (0.0f - Yv) * C_DT + C_SIGY * C_SQDT * zY;
        cYt *= cYfac;

        // clip W at LB_W (no exp/log round-trip; carry W and L together)
        const float We = __expf(Lnew);
        if (We < C_LBW) {
            L = C_LOGLBW; W = C_LBW;
            gW = 0.0f; gY = 0.0f; hWW = 0.0f; hWY = 0.0f;
        } else {
            L = Lnew; W = We;
            gW = gWn; gY = gYn; hWW = hWWn; hWY = hWYn;
        }
        tmt -= C_DT;
    }

    // terminal utility U = W_T^(1-5)/(1-5) = -0.25*exp(-4L); dU/dL = E, d2U/dL2 = -4E
    const float E   = __expf(-4.0f * L);
    const float d1  = E * gW;                                 // dU/dW0
    const float d2v = fmaf(-4.0f * E, gW * gW, E * hWW);      // d2U/dW0^2
    const float d3v = fmaf(-4.0f * E, gW * gY, E * hWY);      // d2U/dW0dY0

    if (lane == 0) {
        atomicAdd(&ws[i],          0.5f * d1);
        atomicAdd(&ws[NPTS + i],   0.5f * d2v);
        atomicAdd(&ws[2*NPTS + i], 0.5f * d3v);
    }
}

__global__ void proj_kernel(const float* __restrict__ ws,
                            const float* __restrict__ Wp,
                            const float* __restrict__ Yp,
                            float* __restrict__ out)
{
    const int i = threadIdx.x;
    if (i >= NPTS) return;
    // lam = S1/128^3 ; dlamW,dlamY = S2,S3/128^4  (exact powers of two)
    const float lam   = ws[i]          * (1.0f / 2097152.0f);
    const float dlamW = ws[NPTS + i]   * (1.0f / 268435456.0f);
    const float dlamY = ws[2*NPTS + i] * (1.0f / 268435456.0f);
    const float Wv = Wp[i], Yv = Yp[i];
    const float mmr   = C_SIGMA * (C_ALPHA * Yv);
    const float sig2  = C_SIGMA * C_SIGMA;
    const float coeff = -1.0f / (Wv * dlamW + 1e-8f);
    const float myo   = coeff * (lam * (mmr / sig2));
    const float hedge = coeff * (C_SIGMA * C_RHO * C_SIGY * dlamY / sig2);
    float v = myo + hedge;
    v = fminf(fmaxf(v, -2.0f), 2.0f);
    out[i] = v;
}

extern "C" void kernel_launch(void* const* d_in, const int* in_sizes, int n_in,
                              void* d_out, int out_size, void* d_ws, size_t ws_size,
                              hipStream_t stream) {
    const float* Wp    = (const float*)d_in[0];
    // d_in[1] = TmT (unused: reference simulates from T_H constant)
    const float* Yp    = (const float*)d_in[2];
    const float* noise = (const float*)d_in[3];
    const float* w1    = (const float*)d_in[4];
    const float* b1    = (const float*)d_in[5];
    const float* w2    = (const float*)d_in[6];
    const float* b2    = (const float*)d_in[7];
    const float* w3    = (const float*)d_in[8];
    const float* b3    = (const float*)d_in[9];
    float* out = (float*)d_out;
    float* ws  = (float*)d_ws;

    hipLaunchKernelGGL(zero_ws, dim3(1), dim3(96), 0, stream, ws);
    hipLaunchKernelGGL(sim_kernel, dim3(NSIM/4), dim3(256), 0, stream,
                       noise, w1, b1, w2, b2, w3, b3, Wp, Yp, ws);
    hipLaunchKernelGGL(proj_kernel, dim3(1), dim3(64), 0, stream, ws, Wp, Yp, out);
}

// Round 4
// 521.707 us; speedup vs baseline: 2.0014x; 1.2317x over previous
//
#include <hip/hip_runtime.h>
#include <math.h>

#define HID    64
#define MSTEPS 60
#define NPTS   32
#define RPTSC  128
#define BTOT   (RPTSC*NPTS)    // 4096 paths
#define NSIM   (2*BTOT)        // 8192 path-branches (antithetic)

// hard-coded model constants (match reference, fp32 semantics)
#define C_DT     0.025f
#define C_SQDT   0.15811388300841897f   // sqrt(0.025)
#define C_ALPHA  0.8f
#define C_RHO    0.3f
#define C_SQ1MR2 0.9539392014169456f    // sqrt(1-0.09)
#define C_KAPPA  1.2f
#define C_R      0.02f
#define C_SIGMA  0.2f
#define C_SIGY   0.3f
#define C_LBW    1e-3f
#define C_LOGLBW -6.907755279f          // log(1e-3)

// NOTE: __builtin_amdgcn_cvt_pkrtz returns __fp16-based vector on this clang;
// _Float16 vector is a distinct non-converting type (R3 compile failure).
typedef __fp16 h2 __attribute__((ext_vector_type(2)));

__device__ __forceinline__ h2 bc_h2(int v) { return __builtin_bit_cast(h2, v); }
__device__ __forceinline__ int bc_i(h2 v)  { return __builtin_bit_cast(int, v); }

#if __has_builtin(__builtin_amdgcn_fdot2)
__device__ __forceinline__ float DOT2(h2 a, h2 b, float c) {
    return __builtin_amdgcn_fdot2(a, b, c, false);
}
#else
__device__ __forceinline__ float DOT2(h2 a, h2 b, float c) {
    return fmaf((float)a.x, (float)b.x, fmaf((float)a.y, (float)b.y, c));
}
#endif

// tanh(x) = 1 - 2/(e^{2x}+1); v_exp + v_rcp, ~1e-6 rel err, saturates correctly
__device__ __forceinline__ float ftanh(float x) {
    float e = __expf(2.0f * x);
    return 1.0f - 2.0f * __builtin_amdgcn_rcpf(e + 1.0f);
}

__global__ void zero_ws(float* ws) {
    ws[threadIdx.x] = 0.0f;   // 96 floats: S1[32], S2[32], S3[32]
}

__global__ __launch_bounds__(256, 2) void sim_kernel(
    const float* __restrict__ noise,
    const float* __restrict__ w1, const float* __restrict__ b1,
    const float* __restrict__ w2, const float* __restrict__ b2,
    const float* __restrict__ w3, const float* __restrict__ b3,
    const float* __restrict__ Wp, const float* __restrict__ Yp,
    float* __restrict__ ws)
{
    const int lane = threadIdx.x & 63;
    // wave id; readfirstlane -> provably wave-uniform so noise loads scalarize
    const int wid = __builtin_amdgcn_readfirstlane(
        (int)((blockIdx.x * blockDim.x + threadIdx.x) >> 6));   // 0..8191
    const int simb = wid >> 12;          // 0: anti=+1 branch, 1: anti=-1 branch
    const int b    = wid & (BTOT - 1);   // path index 0..4095
    const int i    = b & (NPTS - 1);     // eval-point index (b = r*32 + i)
    const float anti = simb ? -1.0f : 1.0f;

    // per-lane (= per hidden unit) weights
    const float cW  = w1[lane];          // w1[0][k] : d a1/dW (constant)
    const float cT  = w1[HID + lane];    // w1[1][k]
    const float cYw = w1[2*HID + lane];  // w1[2][k] : d a1/dY (constant)
    const float b1k = b1[lane];
    const float b2k = b2[lane];
    const float w3k = w3[lane];
    const float b3v = b3[0];
    const float cW2  = cW * cW;
    const float cWYc = cW * cYw;

    // w2 packed f16 pairs along j: w2h[jj] = (w2[2jj][lane], w2[2jj+1][lane]).
    // Kept as ints + opaque asm barrier so the allocator must keep them in VGPRs
    // (cannot rematerialize the global loads inside the loop).
    int w2h[32];
    #pragma unroll
    for (int jj = 0; jj < 32; ++jj) {
        w2h[jj] = bc_i(__builtin_amdgcn_cvt_pkrtz(w2[(2*jj)*HID + lane],
                                                  w2[(2*jj+1)*HID + lane]));
        asm volatile("" : "+v"(w2h[jj]));
    }

    // uniform noise base pointers: noise[sim][draw][m][b]
    const float* zp1 = noise + (size_t)(simb*2 + 0) * MSTEPS * BTOT + b;
    const float* zp2 = noise + (size_t)(simb*2 + 1) * MSTEPS * BTOT + b;

    // state + jets of L = logW: gW=dL/dW0, gY=dL/dY0, hWW=d2L/dW0^2, hWY=d2L/dW0dY0
    const float W0 = Wp[i];
    float L   = __logf(fmaxf(W0, C_LBW));
    float W   = __expf(L);
    float Yv  = Yp[i];
    float tmt = 1.5f;
    float gW  = 1.0f / W0;
    float hWW = -gW * gW;
    float gY  = 0.0f, hWY = 0.0f;
    float cYt = 1.0f;                       // dY_t/dY0 = (1-kappa*dt)^t
    const float cYfac = 1.0f - C_KAPPA * C_DT;

    #pragma unroll 1
    for (int m = 0; m < MSTEPS; ++m) {
        const float z1 = zp1[m * BTOT];     // uniform -> s_load
        const float z2 = zp2[m * BTOT];

        // ---- layer 1 + tanh, build 5 channel inputs (value, dW, dY, dWW, dWY)
        const float a1 = fmaf(W, cW, fmaf(tmt, cT, fmaf(Yv, cYw, b1k)));
        const float t  = ftanh(a1);
        const float dp = 1.0f - t * t;         // tanh'
        const float ddp = -2.0f * t * dp;      // tanh''
        const float s0 = t;
        const float s1 = dp * cW;
        const float s2 = dp * cYw;
        const float s3 = ddp * cW2;
        const float s4 = ddp * cWYc;

        // ---- pack channel pairs across adjacent lanes (valid on even lanes):
        // even lane 2j holds (s[2j], s[2j+1]) as f16x2
        const int pk0 = bc_i(__builtin_amdgcn_cvt_pkrtz(s0, __shfl_xor(s0, 1, 64)));
        const int pk1 = bc_i(__builtin_amdgcn_cvt_pkrtz(s1, __shfl_xor(s1, 1, 64)));
        const int pk2 = bc_i(__builtin_amdgcn_cvt_pkrtz(s2, __shfl_xor(s2, 1, 64)));
        const int pk3 = bc_i(__builtin_amdgcn_cvt_pkrtz(s3, __shfl_xor(s3, 1, 64)));
        const int pk4 = bc_i(__builtin_amdgcn_cvt_pkrtz(s4, __shfl_xor(s4, 1, 64)));

        // ---- layer 2: a2_c[k] = sum_j s_c[j] * w2[j][k]
        // per j-pair: 1 v_readlane (SGPR broadcast) + 1 v_dot2_f32_f16 per channel
        float a0 = b2k, aW = 0.0f, aY = 0.0f, aWW = 0.0f, aWY = 0.0f;
        #pragma unroll
        for (int jj = 0; jj < 32; ++jj) {
            const h2 wv = bc_h2(w2h[jj]);
            a0  = DOT2(bc_h2(__builtin_amdgcn_readlane(pk0, 2*jj)), wv, a0);
            aW  = DOT2(bc_h2(__builtin_amdgcn_readlane(pk1, 2*jj)), wv, aW);
            aY  = DOT2(bc_h2(__builtin_amdgcn_readlane(pk2, 2*jj)), wv, aY);
            aWW = DOT2(bc_h2(__builtin_amdgcn_readlane(pk3, 2*jj)), wv, aWW);
            aWY = DOT2(bc_h2(__builtin_amdgcn_readlane(pk4, 2*jj)), wv, aWY);
        }

        // ---- tanh with full second-order jets
        const float t2  = ftanh(a0);
        const float d2  = 1.0f - t2 * t2;
        const float dd2 = -2.0f * t2 * d2;
        const float h0 = t2;
        const float h1 = d2 * aW;
        const float h2v = d2 * aY;
        const float h3 = fmaf(dd2 * aW, aW, d2 * aWW);
        const float h4 = fmaf(dd2 * aW, aY, d2 * aWY);

        // ---- layer 3: 5 dot products over lanes
        float p0 = h0 * w3k, p1 = h1 * w3k, p2 = h2v * w3k, p3 = h3 * w3k, p4 = h4 * w3k;
        #pragma unroll
        for (int off = 32; off >= 1; off >>= 1) {
            p0 += __shfl_xor(p0, off, 64);
            p1 += __shfl_xor(p1, off, 64);
            p2 += __shfl_xor(p2, off, 64);
            p3 += __shfl_xor(p3, off, 64);
            p4 += __shfl_xor(p4, off, 64);
        }
        const float pi  = p0 + b3v;            // policy value
        const float pW  = p1, pY = p2, pWW = p3, pWY = p4;  // derivs wrt (W,Y)
        // convert W-derivs to L-derivs (W = e^L)
        const float piL  = pW * W;
        const float piLL = fmaf(pWW, W * W, pW * W);
        const float piY  = pY;
        const float piLY = pWY * W;

        const float zW = anti * z1;
        const float zY = anti * (C_RHO * z1 + C_SQ1MR2 * z2);
        const float Sn = C_SIGMA * C_SQDT * zW;               // sigma*sqrt(dt)*zW
        const float G  = C_SIGMA * C_ALPHA * Yv - pi * (C_SIGMA * C_SIGMA);  // dDrift/dpi

        const float drift = C_R + pi * (C_SIGMA * C_ALPHA * Yv);
        const float var   = (pi * C_SIGMA) * (pi * C_SIGMA);
        const float Lnew  = L + (drift - 0.5f * var) * C_DT + pi * Sn;

        // step-map partials F(L,Y)
        const float F_L  = 1.0f + (G * piL) * C_DT + piL * Sn;
        const float F_Y  = (G * piY + pi * C_SIGMA * C_ALPHA) * C_DT + piY * Sn;
        const float F_LL = (G * piLL - C_SIGMA * C_SIGMA * piL * piL) * C_DT + piLL * Sn;
        const float F_LY = (G * piLY - C_SIGMA * C_SIGMA * piL * piY + C_SIGMA * C_ALPHA * piL) * C_DT
                           + piLY * Sn;

        // jet updates (use old values on RHS)
        const float hWWn = F_LL * gW * gW + F_L * hWW;
        const float hWYn = F_LL * gW * gY + F_LY * gW * cYt + F_L * hWY;
        const float gWn  = F_L * gW;
        const float gYn  = F_L * gY + F_Y * cYt;

        // Y update (linear, independent of W)
        Yv  = Yv + C_KAPPA * (0.0f - Yv) * C_DT + C_SIGY * C_SQDT * zY;
        cYt *= cYfac;

        // clip W at LB_W (no exp/log round-trip; carry W and L together)
        const float We = __expf(Lnew);
        if (We < C_LBW) {
            L = C_LOGLBW; W = C_LBW;
            gW = 0.0f; gY = 0.0f; hWW = 0.0f; hWY = 0.0f;
        } else {
            L = Lnew; W = We;
            gW = gWn; gY = gYn; hWW = hWWn; hWY = hWYn;
        }
        tmt -= C_DT;
    }

    // terminal utility U = W_T^(1-5)/(1-5) = -0.25*exp(-4L); dU/dL = E, d2U/dL2 = -4E
    const float E   = __expf(-4.0f * L);
    const float d1  = E * gW;                                 // dU/dW0
    const float d2v = fmaf(-4.0f * E, gW * gW, E * hWW);      // d2U/dW0^2
    const float d3v = fmaf(-4.0f * E, gW * gY, E * hWY);      // d2U/dW0dY0

    if (lane == 0) {
        atomicAdd(&ws[i],          0.5f * d1);
        atomicAdd(&ws[NPTS + i],   0.5f * d2v);
        atomicAdd(&ws[2*NPTS + i], 0.5f * d3v);
    }
}

__global__ void proj_kernel(const float* __restrict__ ws,
                            const float* __restrict__ Wp,
                            const float* __restrict__ Yp,
                            float* __restrict__ out)
{
    const int i = threadIdx.x;
    if (i >= NPTS) return;
    // lam = S1/128^3 ; dlamW,dlamY = S2,S3/128^4  (exact powers of two)
    const float lam   = ws[i]          * (1.0f / 2097152.0f);
    const float dlamW = ws[NPTS + i]   * (1.0f / 268435456.0f);
    const float dlamY = ws[2*NPTS + i] * (1.0f / 268435456.0f);
    const float Wv = Wp[i], Yv = Yp[i];
    const float mmr   = C_SIGMA * (C_ALPHA * Yv);
    const float sig2  = C_SIGMA * C_SIGMA;
    const float coeff = -1.0f / (Wv * dlamW + 1e-8f);
    const float myo   = coeff * (lam * (mmr / sig2));
    const float hedge = coeff * (C_SIGMA * C_RHO * C_SIGY * dlamY / sig2);
    float v = myo + hedge;
    v = fminf(fmaxf(v, -2.0f), 2.0f);
    out[i] = v;
}

extern "C" void kernel_launch(void* const* d_in, const int* in_sizes, int n_in,
                              void* d_out, int out_size, void* d_ws, size_t ws_size,
                              hipStream_t stream) {
    const float* Wp    = (const float*)d_in[0];
    // d_in[1] = TmT (unused: reference simulates from T_H constant)
    const float* Yp    = (const float*)d_in[2];
    const float* noise = (const float*)d_in[3];
    const float* w1    = (const float*)d_in[4];
    const float* b1    = (const float*)d_in[5];
    const float* w2    = (const float*)d_in[6];
    const float* b2    = (const float*)d_in[7];
    const float* w3    = (const float*)d_in[8];
    const float* b3    = (const float*)d_in[9];
    float* out = (float*)d_out;
    float* ws  = (float*)d_ws;

    hipLaunchKernelGGL(zero_ws, dim3(1), dim3(96), 0, stream, ws);
    hipLaunchKernelGGL(sim_kernel, dim3(NSIM/4), dim3(256), 0, stream,
                       noise, w1, b1, w2, b2, w3, b3, Wp, Yp, ws);
    hipLaunchKernelGGL(proj_kernel, dim3(1), dim3(64), 0, stream, ws, Wp, Yp, out);
}

// Round 5
// 258.548 us; speedup vs baseline: 4.0385x; 2.0178x over previous
//
#include <hip/hip_runtime.h>
#include <math.h>

#define HID    64
#define MSTEPS 60
#define NPTS   32
#define RPTSC  128
#define BTOT   (RPTSC*NPTS)    // 4096 paths
#define NSIM   (2*BTOT)        // 8192 path-branches (antithetic)

// hard-coded model constants (match reference, fp32 semantics)
#define C_DT     0.025f
#define C_SQDT   0.15811388300841897f   // sqrt(0.025)
#define C_ALPHA  0.8f
#define C_RHO    0.3f
#define C_SQ1MR2 0.9539392014169456f    // sqrt(1-0.09)
#define C_KAPPA  1.2f
#define C_R      0.02f
#define C_SIGMA  0.2f
#define C_SIGY   0.3f
#define C_LBW    1e-3f
#define C_LOGLBW -6.907755279f          // log(1e-3)

// per-wave LDS layout (stride 3584 B):
//   [0,2304)    A-buffer: 16 rows x 144 B (64 f16 + 16 B pad; pad kills the
//               16-way b128 conflict: bank base = 4*(m+q) mod 32 -> 2-way)
//   [2304,3328) D-main:  float4[64]  (a0,aW,aY,aWW per output unit; dense)
//   [3328,3584) D-aux:   float[64]   (aWY per output unit)
#define WAVE_LDS 3584
#define A_ROW    144
#define OFF_DV   2304
#define OFF_DA   3328

typedef _Float16 half8 __attribute__((ext_vector_type(8)));
typedef float    f32x4 __attribute__((ext_vector_type(4)));

__device__ __forceinline__ float rlanef(float v, int l) {
    return __int_as_float(__builtin_amdgcn_readlane(__float_as_int(v), l));
}

__device__ __forceinline__ f32x4 MFMA(half8 a, half8 b, f32x4 c) {
    return __builtin_amdgcn_mfma_f32_16x16x32_f16(a, b, c, 0, 0, 0);
}

// tanh(x) = 1 - 2/(e^{2x}+1); v_exp + v_rcp, ~1e-6 rel err, saturates correctly
__device__ __forceinline__ float ftanh(float x) {
    float e = __expf(2.0f * x);
    return 1.0f - 2.0f * __builtin_amdgcn_rcpf(e + 1.0f);
}

__global__ void zero_ws(float* ws) {
    ws[threadIdx.x] = 0.0f;   // 96 floats: S1[32], S2[32], S3[32]
}

__global__ __launch_bounds__(256) __attribute__((amdgpu_waves_per_eu(2, 4)))
void sim_kernel(
    const float* __restrict__ noise,
    const float* __restrict__ w1, const float* __restrict__ b1,
    const float* __restrict__ w2, const float* __restrict__ b2,
    const float* __restrict__ w3, const float* __restrict__ b3,
    const float* __restrict__ Wp, const float* __restrict__ Yp,
    float* __restrict__ ws)
{
    __shared__ __align__(16) char smem[4 * WAVE_LDS];
    const int lane = threadIdx.x & 63;
    const int quad = lane >> 4;      // 0..3
    const int mrow = lane & 15;      // 0..15
    char* wb = smem + (threadIdx.x >> 6) * WAVE_LDS;

    const int wid = __builtin_amdgcn_readfirstlane(
        (int)((blockIdx.x * blockDim.x + threadIdx.x) >> 6));   // 0..8191
    const int simb = wid >> 12;
    const int b    = wid & (BTOT - 1);
    const int i    = b & (NPTS - 1);
    const float anti = simb ? -1.0f : 1.0f;

    // per-lane layer-1 weights (lane = hidden unit)
    const float cW  = w1[lane];
    const float cT  = w1[HID + lane];
    const float cYw = w1[2*HID + lane];
    const float b1k = b1[lane];
    const float b2k = b2[lane];
    const float b3v = b3[0];
    const float cW2  = cW * cW;
    const float cWYc = cW * cYw;

    // ---- preload MFMA B fragments (f16), layout B[k][n]: n=mrow+t*16, k=q*32+quad*8+j
    half8 w2f[2][4];
    #pragma unroll
    for (int q = 0; q < 2; ++q)
        #pragma unroll
        for (int t = 0; t < 4; ++t) {
            half8 h;
            #pragma unroll
            for (int j = 0; j < 8; ++j)
                h[j] = (_Float16)w2[(q*32 + quad*8 + j)*HID + t*16 + mrow];
            w2f[q][t] = h;
        }
    half8 w3f[2];   // B[k][n] = w3[k] broadcast over n
    #pragma unroll
    for (int q = 0; q < 2; ++q) {
        half8 h;
        #pragma unroll
        for (int j = 0; j < 8; ++j)
            h[j] = (_Float16)w3[q*32 + quad*8 + j];
        w3f[q] = h;
    }

    // zero A-buffer rows 5..15 (never written again; provide zero M-rows to MFMA)
    for (int off = 5*A_ROW + lane*4; off < 16*A_ROW; off += 256)
        *(float*)(wb + off) = 0.0f;

    // LDS addresses
    _Float16* swp = (_Float16*)(wb + lane*2);              // channel row c at +c*72 elems
    char* arp0 = wb + mrow*A_ROW + quad*16;                // A-frag k-iter 0
    // k-iter 1 at +64 bytes

    // uniform noise base pointers
    const float* zp1 = noise + (size_t)(simb*2 + 0) * MSTEPS * BTOT + b;
    const float* zp2 = noise + (size_t)(simb*2 + 1) * MSTEPS * BTOT + b;

    // state + jets of L = logW
    const float W0 = Wp[i];
    float L   = __logf(fmaxf(W0, C_LBW));
    float W   = __expf(L);
    float Yv  = Yp[i];
    float tmt = 1.5f;
    float gW  = 1.0f / W0;
    float hWW = -gW * gW;
    float gY  = 0.0f, hWY = 0.0f;
    float cYt = 1.0f;
    const float cYfac = 1.0f - C_KAPPA * C_DT;

    #pragma unroll 1
    for (int m = 0; m < MSTEPS; ++m) {
        const float z1 = zp1[m * BTOT];
        const float z2 = zp2[m * BTOT];

        // ---- layer 1 + tanh: 5 channels (value, dW, dY, dWW, dWY), lane = unit j
        const float a1 = fmaf(W, cW, fmaf(tmt, cT, fmaf(Yv, cYw, b1k)));
        const float t1 = ftanh(a1);
        const float dp  = 1.0f - t1 * t1;
        const float ddp = -2.0f * t1 * dp;

        // ---- marshal A (5 x 64, f16) rows 0..4
        swp[0]     = (_Float16)t1;
        swp[72]    = (_Float16)(dp * cW);
        swp[144]   = (_Float16)(dp * cYw);
        swp[216]   = (_Float16)(ddp * cW2);
        swp[288]   = (_Float16)(ddp * cWYc);

        half8 af0 = __builtin_bit_cast(half8, *(const f32x4*)arp0);
        half8 af1 = __builtin_bit_cast(half8, *(const f32x4*)(arp0 + 64));

        // ---- layer 2 GEMM: (16x64)x(64x64) via 4 N-tiles x 2 K-iters
        f32x4 acc[4];
        #pragma unroll
        for (int t = 0; t < 4; ++t) {
            f32x4 z = {0.f, 0.f, 0.f, 0.f};
            acc[t] = MFMA(af0, w2f[0][t], z);
            acc[t] = MFMA(af1, w2f[1][t], acc[t]);
        }

        // ---- transpose D back: rows 0..3 (a0,aW,aY,aWW) live in quad0 regs,
        //      row 4 (aWY) in quad1 reg0. col n = t*16+mrow.
        if (quad == 0) {
            #pragma unroll
            for (int t = 0; t < 4; ++t)
                *(f32x4*)(wb + OFF_DV + (t*16 + mrow)*16) = acc[t];
        } else if (quad == 1) {
            #pragma unroll
            for (int t = 0; t < 4; ++t)
                *(float*)(wb + OFF_DA + (t*16 + mrow)*4) = acc[t].x;
        }
        const f32x4 av  = *(const f32x4*)(wb + OFF_DV + lane*16);
        const float aWY = *(const float*)(wb + OFF_DA + lane*4);
        const float a0 = av.x + b2k, aW = av.y, aY = av.z, aWW = av.w;

        // ---- tanh with full second-order jets (lane = unit k)
        const float t2  = ftanh(a0);
        const float d2  = 1.0f - t2 * t2;
        const float dd2 = -2.0f * t2 * d2;
        const float h0 = t2;
        const float h1 = d2 * aW;
        const float h2 = d2 * aY;
        const float h3 = fmaf(dd2 * aW, aW, d2 * aWW);
        const float h4 = fmaf(dd2 * aW, aY, d2 * aWY);

        // ---- layer 3 via MFMA: A rows = h-channels, B = w3 broadcast
        swp[0]   = (_Float16)h0;
        swp[72]  = (_Float16)h1;
        swp[144] = (_Float16)h2;
        swp[216] = (_Float16)h3;
        swp[288] = (_Float16)h4;
        half8 bf0 = __builtin_bit_cast(half8, *(const f32x4*)arp0);
        half8 bf1 = __builtin_bit_cast(half8, *(const f32x4*)(arp0 + 64));
        f32x4 z4 = {0.f, 0.f, 0.f, 0.f};
        f32x4 acc4 = MFMA(bf0, w3f[0], z4);
        acc4 = MFMA(bf1, w3f[1], acc4);
        // D rows 0..3 -> lane 0 regs 0..3 ; row 4 -> lane 16 reg 0
        const float pi  = rlanef(acc4.x, 0) + b3v;
        const float pW  = rlanef(acc4.y, 0);
        const float pY  = rlanef(acc4.z, 0);
        const float pWW = rlanef(acc4.w, 0);
        const float pWY = rlanef(acc4.x, 16);

        // convert W-derivs to L-derivs (W = e^L)
        const float piL  = pW * W;
        const float piLL = fmaf(pWW, W * W, pW * W);
        const float piY  = pY;
        const float piLY = pWY * W;

        const float zW = anti * z1;
        const float zY = anti * (C_RHO * z1 + C_SQ1MR2 * z2);
        const float Sn = C_SIGMA * C_SQDT * zW;
        const float G  = C_SIGMA * C_ALPHA * Yv - pi * (C_SIGMA * C_SIGMA);

        const float drift = C_R + pi * (C_SIGMA * C_ALPHA * Yv);
        const float var   = (pi * C_SIGMA) * (pi * C_SIGMA);
        const float Lnew  = L + (drift - 0.5f * var) * C_DT + pi * Sn;

        const float F_L  = 1.0f + (G * piL) * C_DT + piL * Sn;
        const float F_Y  = (G * piY + pi * C_SIGMA * C_ALPHA) * C_DT + piY * Sn;
        const float F_LL = (G * piLL - C_SIGMA * C_SIGMA * piL * piL) * C_DT + piLL * Sn;
        const float F_LY = (G * piLY - C_SIGMA * C_SIGMA * piL * piY + C_SIGMA * C_ALPHA * piL) * C_DT
                           + piLY * Sn;

        const float hWWn = F_LL * gW * gW + F_L * hWW;
        const float hWYn = F_LL * gW * gY + F_LY * gW * cYt + F_L * hWY;
        const float gWn  = F_L * gW;
        const float gYn  = F_L * gY + F_Y * cYt;

        Yv  = Yv + C_KAPPA * (0.0f - Yv) * C_DT + C_SIGY * C_SQDT * zY;
        cYt *= cYfac;

        const float We = __expf(Lnew);
        if (We < C_LBW) {
            L = C_LOGLBW; W = C_LBW;
            gW = 0.0f; gY = 0.0f; hWW = 0.0f; hWY = 0.0f;
        } else {
            L = Lnew; W = We;
            gW = gWn; gY = gYn; hWW = hWWn; hWY = hWYn;
        }
        tmt -= C_DT;
    }

    // terminal utility U = -0.25*exp(-4L); dU/dL = E, d2U/dL2 = -4E
    const float E   = __expf(-4.0f * L);
    const float d1  = E * gW;
    const float d2v = fmaf(-4.0f * E, gW * gW, E * hWW);
    const float d3v = fmaf(-4.0f * E, gW * gY, E * hWY);

    if (lane == 0) {
        atomicAdd(&ws[i],          0.5f * d1);
        atomicAdd(&ws[NPTS + i],   0.5f * d2v);
        atomicAdd(&ws[2*NPTS + i], 0.5f * d3v);
    }
}

__global__ void proj_kernel(const float* __restrict__ ws,
                            const float* __restrict__ Wp,
                            const float* __restrict__ Yp,
                            float* __restrict__ out)
{
    const int i = threadIdx.x;
    if (i >= NPTS) return;
    const float lam   = ws[i]          * (1.0f / 2097152.0f);
    const float dlamW = ws[NPTS + i]   * (1.0f / 268435456.0f);
    const float dlamY = ws[2*NPTS + i] * (1.0f / 268435456.0f);
    const float Wv = Wp[i], Yv = Yp[i];
    const float mmr   = C_SIGMA * (C_ALPHA * Yv);
    const float sig2  = C_SIGMA * C_SIGMA;
    const float coeff = -1.0f / (Wv * dlamW + 1e-8f);
    const float myo   = coeff * (lam * (mmr / sig2));
    const float hedge = coeff * (C_SIGMA * C_RHO * C_SIGY * dlamY / sig2);
    float v = myo + hedge;
    v = fminf(fmaxf(v, -2.0f), 2.0f);
    out[i] = v;
}

extern "C" void kernel_launch(void* const* d_in, const int* in_sizes, int n_in,
                              void* d_out, int out_size, void* d_ws, size_t ws_size,
                              hipStream_t stream) {
    const float* Wp    = (const float*)d_in[0];
    // d_in[1] = TmT (unused: reference simulates from T_H constant)
    const float* Yp    = (const float*)d_in[2];
    const float* noise = (const float*)d_in[3];
    const float* w1    = (const float*)d_in[4];
    const float* b1    = (const float*)d_in[5];
    const float* w2    = (const float*)d_in[6];
    const float* b2    = (const float*)d_in[7];
    const float* w3    = (const float*)d_in[8];
    const float* b3    = (const float*)d_in[9];
    float* out = (float*)d_out;
    float* ws  = (float*)d_ws;

    hipLaunchKernelGGL(zero_ws, dim3(1), dim3(96), 0, stream, ws);
    hipLaunchKernelGGL(sim_kernel, dim3(NSIM/4), dim3(256), 0, stream,
                       noise, w1, b1, w2, b2, w3, b3, Wp, Yp, ws);
    hipLaunchKernelGGL(proj_kernel, dim3(1), dim3(64), 0, stream, ws, Wp, Yp, out);
}

// Round 6
// 205.206 us; speedup vs baseline: 5.0883x; 1.2599x over previous
//
#include <hip/hip_runtime.h>
#include <math.h>

#define HID    64
#define MSTEPS 60
#define NPTS   32
#define RPTSC  128
#define BTOT   (RPTSC*NPTS)    // 4096 paths
#define NSIM   (2*BTOT)        // 8192 path-branches
#define NWAVE  (NSIM/2)        // 4096 waves, 2 path-branches per wave

// hard-coded model constants (match reference, fp32 semantics)
#define C_DT     0.025f
#define C_SQDT   0.15811388300841897f   // sqrt(0.025)
#define C_ALPHA  0.8f
#define C_RHO    0.3f
#define C_SQ1MR2 0.9539392014169456f    // sqrt(1-0.09)
#define C_KAPPA  1.2f
#define C_R      0.02f
#define C_SIGMA  0.2f
#define C_SIGY   0.3f
#define C_LBW    1e-3f
#define C_LOGLBW -6.907755279f          // log(1e-3)

// per-wave LDS layout:
//   [0,2304)      A-buffer: 16 rows x 144 B (64 f16 + 16 B pad)
//                 path p channels at rows 8p..8p+4; rows 5-7,13-15 stay zero
//   [2304,4352)   DV: float4[2][64]  (a0,aW,aY,aWW per path per unit)
//   [4352,4864)   DA: float[2][64]   (aWY per path per unit)
//   [4864,4896)   PV: float4[2]      (pi,pW,pY,pWW per path)
//   [4896,4904)   PA: float[2]       (pWY per path)
#define WAVE_LDS 4928
#define A_ROW    144
#define OFF_DV   2304
#define OFF_DA   4352
#define OFF_PV   4864
#define OFF_PA   4896

typedef _Float16 half8 __attribute__((ext_vector_type(8)));
typedef float    f32x4 __attribute__((ext_vector_type(4)));

__device__ __forceinline__ float rlanef(float v, int l) {
    return __int_as_float(__builtin_amdgcn_readlane(__float_as_int(v), l));
}
__device__ __forceinline__ f32x4 MFMA(half8 a, half8 b, f32x4 c) {
    return __builtin_amdgcn_mfma_f32_16x16x32_f16(a, b, c, 0, 0, 0);
}
// tanh(x) = 1 - 2/(e^{2x}+1)
__device__ __forceinline__ float ftanh(float x) {
    float e = __expf(2.0f * x);
    return 1.0f - 2.0f * __builtin_amdgcn_rcpf(e + 1.0f);
}

__global__ void zero_ws(float* ws) {
    ws[threadIdx.x] = 0.0f;   // 96 floats: S1[32], S2[32], S3[32]
}

__global__ __launch_bounds__(256, 4) void sim_kernel(
    const float* __restrict__ noise,
    const float* __restrict__ w1, const float* __restrict__ b1,
    const float* __restrict__ w2, const float* __restrict__ b2,
    const float* __restrict__ w3, const float* __restrict__ b3,
    const float* __restrict__ Wp, const float* __restrict__ Yp,
    float* __restrict__ ws)
{
    __shared__ __align__(16) char smem[4 * WAVE_LDS];
    const int lane = threadIdx.x & 63;
    const int quad = lane >> 4;      // 0..3
    const int mrow = lane & 15;      // 0..15
    const int par  = lane & 1;       // which of the wave's 2 paths this lane works
    char* wb = smem + (threadIdx.x >> 6) * WAVE_LDS;

    const int w = __builtin_amdgcn_readfirstlane(
        (int)((blockIdx.x * blockDim.x + threadIdx.x) >> 6));   // 0..4095
    const int simb = w >> 11;                 // antithetic branch (uniform per wave)
    const int pg   = 2*(w & 2047) + par;      // per-lane global path 0..4095
    const int i    = pg & (NPTS - 1);         // per-lane eval point
    const float anti = simb ? -1.0f : 1.0f;

    // per-lane layer-1 weights (lane = hidden unit)
    const float cW  = w1[lane];
    const float cT  = w1[HID + lane];
    const float cYw = w1[2*HID + lane];
    const float b1k = b1[lane];
    const float b2k = b2[lane];
    const float b3v = b3[0];
    const float cW2  = cW * cW;
    const float cWYc = cW * cYw;

    // MFMA B fragments (f16): B[k][n], n=mrow+t*16, k=q*32+quad*8+j
    half8 w2f[2][4];
    #pragma unroll
    for (int q = 0; q < 2; ++q)
        #pragma unroll
        for (int t = 0; t < 4; ++t) {
            half8 h;
            #pragma unroll
            for (int j = 0; j < 8; ++j)
                h[j] = (_Float16)w2[(q*32 + quad*8 + j)*HID + t*16 + mrow];
            w2f[q][t] = h;
        }
    half8 w3f[2];   // w3 broadcast over n
    #pragma unroll
    for (int q = 0; q < 2; ++q) {
        half8 h;
        #pragma unroll
        for (int j = 0; j < 8; ++j)
            h[j] = (_Float16)w3[q*32 + quad*8 + j];
        w3f[q] = h;
    }

    // zero entire A-buffer once (rows 5-7, 13-15 must stay zero)
    for (int off = lane*4; off < 16*A_ROW; off += 256)
        *(float*)(wb + off) = 0.0f;

    // LDS addresses
    _Float16* swp = (_Float16*)(wb + lane*2);   // + row*72 elements
    char* arp0 = wb + mrow*A_ROW + quad*16;     // A-frag k-iter 0 (+64 B for iter 1)

    // per-lane noise pointers (lanes differ only in par -> adjacent floats)
    const float* zp1 = noise + (size_t)(simb*2 + 0) * MSTEPS * BTOT + pg;
    const float* zp2 = noise + (size_t)(simb*2 + 1) * MSTEPS * BTOT + pg;

    // per-lane path state + jets of L = logW
    const float W0 = Wp[i];
    float L   = __logf(fmaxf(W0, C_LBW));
    float W   = __expf(L);
    float Yv  = Yp[i];
    float tmt = 1.5f;
    float gW  = 1.0f / W0;
    float hWW = -gW * gW;
    float gY  = 0.0f, hWY = 0.0f;
    float cYt = 1.0f;
    const float cYfac = 1.0f - C_KAPPA * C_DT;

    #pragma unroll 1
    for (int m = 0; m < MSTEPS; ++m) {
        const float z1 = zp1[(size_t)m * BTOT];
        const float z2 = zp2[(size_t)m * BTOT];

        // broadcast both paths' (W,Y) to all lanes (tmt is uniform)
        const float Wb0 = rlanef(W, 0),  Wb1 = rlanef(W, 1);
        const float Yb0 = rlanef(Yv, 0), Yb1 = rlanef(Yv, 1);

        // ---- layer 1 + tanh for both paths; marshal A rows 8p..8p+4
        {
            const float a1 = fmaf(Wb0, cW, fmaf(tmt, cT, fmaf(Yb0, cYw, b1k)));
            const float t1 = ftanh(a1);
            const float dp = 1.0f - t1*t1, ddp = -2.0f*t1*dp;
            swp[0*72] = (_Float16)t1;
            swp[1*72] = (_Float16)(dp * cW);
            swp[2*72] = (_Float16)(dp * cYw);
            swp[3*72] = (_Float16)(ddp * cW2);
            swp[4*72] = (_Float16)(ddp * cWYc);
        }
        {
            const float a1 = fmaf(Wb1, cW, fmaf(tmt, cT, fmaf(Yb1, cYw, b1k)));
            const float t1 = ftanh(a1);
            const float dp = 1.0f - t1*t1, ddp = -2.0f*t1*dp;
            swp[8*72]  = (_Float16)t1;
            swp[9*72]  = (_Float16)(dp * cW);
            swp[10*72] = (_Float16)(dp * cYw);
            swp[11*72] = (_Float16)(ddp * cW2);
            swp[12*72] = (_Float16)(ddp * cWYc);
        }

        half8 af0 = __builtin_bit_cast(half8, *(const f32x4*)arp0);
        half8 af1 = __builtin_bit_cast(half8, *(const f32x4*)(arp0 + 64));

        // ---- layer 2 GEMM: 4 N-tiles x 2 K-iters
        f32x4 acc[4];
        #pragma unroll
        for (int t = 0; t < 4; ++t) {
            f32x4 z = {0.f, 0.f, 0.f, 0.f};
            acc[t] = MFMA(af0, w2f[0][t], z);
            acc[t] = MFMA(af1, w2f[1][t], acc[t]);
        }

        // ---- D transpose: even quads = path quad/2 ch0-3 (rows 8p..8p+3),
        //      odd quads = path quad/2 ch4 (row 8p+4). col n = t*16+mrow.
        {
            const int p = quad >> 1;
            if (!(quad & 1)) {
                #pragma unroll
                for (int t = 0; t < 4; ++t)
                    *(f32x4*)(wb + OFF_DV + (p*64 + t*16 + mrow)*16) = acc[t];
            } else {
                #pragma unroll
                for (int t = 0; t < 4; ++t)
                    *(float*)(wb + OFF_DA + (p*64 + t*16 + mrow)*4) = acc[t].x;
            }
        }

        // ---- per-lane (unit k) read both paths' activations, compute h rows
        const f32x4 av0 = *(const f32x4*)(wb + OFF_DV + lane*16);
        const f32x4 av1 = *(const f32x4*)(wb + OFF_DV + (64 + lane)*16);
        const float awy0 = *(const float*)(wb + OFF_DA + lane*4);
        const float awy1 = *(const float*)(wb + OFF_DA + (64 + lane)*4);
        {
            const float t2 = ftanh(av0.x + b2k);
            const float d2 = 1.0f - t2*t2, dd2 = -2.0f*t2*d2;
            swp[0*72] = (_Float16)t2;
            swp[1*72] = (_Float16)(d2 * av0.y);
            swp[2*72] = (_Float16)(d2 * av0.z);
            swp[3*72] = (_Float16)fmaf(dd2 * av0.y, av0.y, d2 * av0.w);
            swp[4*72] = (_Float16)fmaf(dd2 * av0.y, av0.z, d2 * awy0);
        }
        {
            const float t2 = ftanh(av1.x + b2k);
            const float d2 = 1.0f - t2*t2, dd2 = -2.0f*t2*d2;
            swp[8*72]  = (_Float16)t2;
            swp[9*72]  = (_Float16)(d2 * av1.y);
            swp[10*72] = (_Float16)(d2 * av1.z);
            swp[11*72] = (_Float16)fmaf(dd2 * av1.y, av1.y, d2 * av1.w);
            swp[12*72] = (_Float16)fmaf(dd2 * av1.y, av1.z, d2 * awy1);
        }

        // ---- layer 3 via MFMA (w3 broadcast over n -> all cols equal)
        half8 bf0 = __builtin_bit_cast(half8, *(const f32x4*)arp0);
        half8 bf1 = __builtin_bit_cast(half8, *(const f32x4*)(arp0 + 64));
        f32x4 z4 = {0.f, 0.f, 0.f, 0.f};
        f32x4 acc4 = MFMA(bf0, w3f[0], z4);
        acc4 = MFMA(bf1, w3f[1], acc4);

        // scatter per-path policy jets: rows 8p..8p+3 -> even quads, row 8p+4 -> odd
        if (mrow == 0) {
            const int p = quad >> 1;
            if (!(quad & 1)) *(f32x4*)(wb + OFF_PV + p*16) = acc4;
            else             *(float*)(wb + OFF_PA + p*4)  = acc4.x;
        }
        const f32x4 pv  = *(const f32x4*)(wb + OFF_PV + par*16);
        const float pWY = *(const float*)(wb + OFF_PA + par*4);
        const float pi  = pv.x + b3v;
        const float pW  = pv.y, pY = pv.z, pWW = pv.w;

        // ---- dynamics + jet update (lane-parallel: this lane's path)
        const float piL  = pW * W;
        const float piLL = fmaf(pWW, W * W, pW * W);
        const float piY  = pY;
        const float piLY = pWY * W;

        const float zW = anti * z1;
        const float zY = anti * (C_RHO * z1 + C_SQ1MR2 * z2);
        const float Sn = C_SIGMA * C_SQDT * zW;
        const float G  = C_SIGMA * C_ALPHA * Yv - pi * (C_SIGMA * C_SIGMA);

        const float drift = C_R + pi * (C_SIGMA * C_ALPHA * Yv);
        const float var   = (pi * C_SIGMA) * (pi * C_SIGMA);
        const float Lnew  = L + (drift - 0.5f * var) * C_DT + pi * Sn;

        const float F_L  = 1.0f + (G * piL) * C_DT + piL * Sn;
        const float F_Y  = (G * piY + pi * C_SIGMA * C_ALPHA) * C_DT + piY * Sn;
        const float F_LL = (G * piLL - C_SIGMA * C_SIGMA * piL * piL) * C_DT + piLL * Sn;
        const float F_LY = (G * piLY - C_SIGMA * C_SIGMA * piL * piY + C_SIGMA * C_ALPHA * piL) * C_DT
                           + piLY * Sn;

        const float hWWn = F_LL * gW * gW + F_L * hWW;
        const float hWYn = F_LL * gW * gY + F_LY * gW * cYt + F_L * hWY;
        const float gWn  = F_L * gW;
        const float gYn  = F_L * gY + F_Y * cYt;

        Yv  = Yv + C_KAPPA * (0.0f - Yv) * C_DT + C_SIGY * C_SQDT * zY;
        cYt *= cYfac;

        const float We = __expf(Lnew);
        if (We < C_LBW) {
            L = C_LOGLBW; W = C_LBW;
            gW = 0.0f; gY = 0.0f; hWW = 0.0f; hWY = 0.0f;
        } else {
            L = Lnew; W = We;
            gW = gWn; gY = gYn; hWW = hWWn; hWY = hWYn;
        }
        tmt -= C_DT;
    }

    // terminal utility U = -0.25*exp(-4L)
    const float E   = __expf(-4.0f * L);
    const float d1  = E * gW;
    const float d2v = fmaf(-4.0f * E, gW * gW, E * hWW);
    const float d3v = fmaf(-4.0f * E, gW * gY, E * hWY);

    if (lane < 2) {   // lane 0 = path 2w, lane 1 = path 2w+1 (each has its own i)
        atomicAdd(&ws[i],          0.5f * d1);
        atomicAdd(&ws[NPTS + i],   0.5f * d2v);
        atomicAdd(&ws[2*NPTS + i], 0.5f * d3v);
    }
}

__global__ void proj_kernel(const float* __restrict__ ws,
                            const float* __restrict__ Wp,
                            const float* __restrict__ Yp,
                            float* __restrict__ out)
{
    const int i = threadIdx.x;
    if (i >= NPTS) return;
    const float lam   = ws[i]          * (1.0f / 2097152.0f);
    const float dlamW = ws[NPTS + i]   * (1.0f / 268435456.0f);
    const float dlamY = ws[2*NPTS + i] * (1.0f / 268435456.0f);
    const float Wv = Wp[i], Yv = Yp[i];
    const float mmr   = C_SIGMA * (C_ALPHA * Yv);
    const float sig2  = C_SIGMA * C_SIGMA;
    const float coeff = -1.0f / (Wv * dlamW + 1e-8f);
    const float myo   = coeff * (lam * (mmr / sig2));
    const float hedge = coeff * (C_SIGMA * C_RHO * C_SIGY * dlamY / sig2);
    float v = myo + hedge;
    v = fminf(fmaxf(v, -2.0f), 2.0f);
    out[i] = v;
}

extern "C" void kernel_launch(void* const* d_in, const int* in_sizes, int n_in,
                              void* d_out, int out_size, void* d_ws, size_t ws_size,
                              hipStream_t stream) {
    const float* Wp    = (const float*)d_in[0];
    // d_in[1] = TmT (unused: reference simulates from T_H constant)
    const float* Yp    = (const float*)d_in[2];
    const float* noise = (const float*)d_in[3];
    const float* w1    = (const float*)d_in[4];
    const float* b1    = (const float*)d_in[5];
    const float* w2    = (const float*)d_in[6];
    const float* b2    = (const float*)d_in[7];
    const float* w3    = (const float*)d_in[8];
    const float* b3    = (const float*)d_in[9];
    float* out = (float*)d_out;
    float* ws  = (float*)d_ws;

    hipLaunchKernelGGL(zero_ws, dim3(1), dim3(96), 0, stream, ws);
    hipLaunchKernelGGL(sim_kernel, dim3(NWAVE/4), dim3(256), 0, stream,
                       noise, w1, b1, w2, b2, w3, b3, Wp, Yp, ws);
    hipLaunchKernelGGL(proj_kernel, dim3(1), dim3(64), 0, stream, ws, Wp, Yp, out);
}